// Round 1
// baseline (1811.767 us; speedup 1.0000x reference)
//
#include <hip/hip_runtime.h>
#include <hip/hip_bf16.h>
#include <math.h>

#define INPUT 768
#define HIDDEN 16384
#define ROWS 4096
#define KSP 32

// ---------------- Kernel 1: inverse row norms of W ----------------
// One wave per row (4 rows per 256-thread block).
__global__ __launch_bounds__(256) void rownorm_kernel(const float* __restrict__ W,
                                                      float* __restrict__ inv_norm) {
    int row = blockIdx.x * 4 + (threadIdx.x >> 6);
    int lane = threadIdx.x & 63;
    const float* wr = W + (size_t)row * INPUT;
    float s = 0.f;
    for (int c = lane; c < INPUT; c += 64) { float v = wr[c]; s += v * v; }
    for (int off = 32; off > 0; off >>= 1) s += __shfl_down(s, off, 64);
    if (lane == 0) inv_norm[row] = 1.0f / sqrtf(s);
}

// ---------------- Kernel 2: pre = x @ W^T + b (fp32) ----------------
// 64x64 tile, BK=16, 256 threads, 4x4 micro-tile per thread.
#define BM 64
#define BN 64
#define BK 16

__global__ __launch_bounds__(256) void gemm1_kernel(const float* __restrict__ x,
                                                    const float* __restrict__ W,
                                                    const float* __restrict__ b,
                                                    float* __restrict__ pre) {
    __shared__ float As[BK][BM + 4];   // +4 pad keeps 16B alignment, breaks pow2 stride
    __shared__ float Bs[BK][BN + 4];
    int tid = threadIdx.x;
    int m0 = blockIdx.y * BM;
    int n0 = blockIdx.x * BN;
    int tx = tid & 15;        // n direction
    int ty = tid >> 4;        // m direction
    int lrow = tid >> 2;      // 0..63
    int lk4  = (tid & 3) * 4; // 0,4,8,12

    const float* xa = x + (size_t)(m0 + lrow) * INPUT + lk4;
    const float* wb = W + (size_t)(n0 + lrow) * INPUT + lk4;

    float acc[4][4] = {};

    for (int kt = 0; kt < INPUT; kt += BK) {
        float4 av = *(const float4*)(xa + kt);
        float4 bv = *(const float4*)(wb + kt);
        As[lk4 + 0][lrow] = av.x; As[lk4 + 1][lrow] = av.y;
        As[lk4 + 2][lrow] = av.z; As[lk4 + 3][lrow] = av.w;
        Bs[lk4 + 0][lrow] = bv.x; Bs[lk4 + 1][lrow] = bv.y;
        Bs[lk4 + 2][lrow] = bv.z; Bs[lk4 + 3][lrow] = bv.w;
        __syncthreads();
        #pragma unroll
        for (int k = 0; k < BK; ++k) {
            float4 a4 = *(const float4*)&As[k][ty * 4];
            float4 b4 = *(const float4*)&Bs[k][tx * 4];
            float a[4] = {a4.x, a4.y, a4.z, a4.w};
            float bb[4] = {b4.x, b4.y, b4.z, b4.w};
            #pragma unroll
            for (int i = 0; i < 4; ++i)
                #pragma unroll
                for (int j = 0; j < 4; ++j)
                    acc[i][j] += a[i] * bb[j];
        }
        __syncthreads();
    }

    float bvals[4];
    #pragma unroll
    for (int j = 0; j < 4; ++j) bvals[j] = b[n0 + tx * 4 + j];
    #pragma unroll
    for (int i = 0; i < 4; ++i) {
        int m = m0 + ty * 4 + i;
        float4 o;
        o.x = acc[i][0] + bvals[0];
        o.y = acc[i][1] + bvals[1];
        o.z = acc[i][2] + bvals[2];
        o.w = acc[i][3] + bvals[3];
        *(float4*)(pre + (size_t)m * HIDDEN + n0 + tx * 4) = o;
    }
}

// ---------------- Kernel 3: per-row exact top-32 select + mask + sparse decode ----------------
// One 256-thread block per row. Row (16384 floats) held in registers as
// monotonic uint keys (64/thread). Exact 32-iteration bisection on key space
// finds the 32nd-largest value (no LDS-atomic histogram: N(0,1) exponent
// clustering would serialize atomics). Then masked encoded write + LDS
// compaction of selected (idx,val), then sparse decoded = sum v*inv_norm[j]*W[j,:].
__device__ __forceinline__ unsigned int f2key(float f) {
    unsigned int u = __float_as_uint(f);
    return (u & 0x80000000u) ? ~u : (u | 0x80000000u);
}
__device__ __forceinline__ float key2f(unsigned int k) {
    unsigned int u = (k & 0x80000000u) ? (k & 0x7FFFFFFFu) : ~k;
    return __uint_as_float(u);
}

__global__ __launch_bounds__(256) void topk_kernel(float* __restrict__ enc,      // in: pre, out: masked
                                                   const float* __restrict__ W,
                                                   const float* __restrict__ inv_norm,
                                                   float* __restrict__ dec) {
    __shared__ unsigned int wsum[4];
    __shared__ unsigned int s_cnt;
    __shared__ int   sel_idx[512];
    __shared__ float sel_val[512];

    int tid = threadIdx.x;
    int r = blockIdx.x;
    float* erow = enc + (size_t)r * HIDDEN;

    // Load row as keys: thread t owns float4 chunks at float4-index (t + 256*i)
    uint4 u[16];
    #pragma unroll
    for (int i = 0; i < 16; ++i) {
        float4 v = ((const float4*)erow)[tid + i * 256];
        u[i].x = f2key(v.x); u[i].y = f2key(v.y);
        u[i].z = f2key(v.z); u[i].w = f2key(v.w);
    }
    if (tid == 0) s_cnt = 0;

    // Bisection: largest t such that count(key >= t) >= 32  -> exact 32nd-largest key
    unsigned int lo = 0u, hi = 0xFFFFFFFFu;
    for (int it = 0; it < 32; ++it) {
        unsigned int mid = (unsigned int)(((unsigned long long)lo + (unsigned long long)hi + 1ull) >> 1);
        int c = 0;
        #pragma unroll
        for (int i = 0; i < 16; ++i) {
            c += (u[i].x >= mid) + (u[i].y >= mid) + (u[i].z >= mid) + (u[i].w >= mid);
        }
        for (int off = 32; off > 0; off >>= 1) c += __shfl_down(c, off, 64);
        if ((tid & 63) == 0) wsum[tid >> 6] = (unsigned int)c;
        __syncthreads();
        unsigned int total = wsum[0] + wsum[1] + wsum[2] + wsum[3];
        if (total >= (unsigned int)KSP) lo = mid; else hi = mid - 1;
        __syncthreads();
    }
    unsigned int kth = lo;  // key of 32nd-largest; >= kth selects (ties included, matches pre>=thresh)

    // Masked encoded write + compaction of selected entries
    #pragma unroll
    for (int i = 0; i < 16; ++i) {
        int jbase = (tid + i * 256) * 4;
        unsigned int uu[4] = {u[i].x, u[i].y, u[i].z, u[i].w};
        float4 o;
        float vv[4];
        #pragma unroll
        for (int c = 0; c < 4; ++c) {
            bool sel = uu[c] >= kth;
            float f = key2f(uu[c]);
            vv[c] = sel ? f : 0.0f;
            if (sel) {
                unsigned int p = atomicAdd(&s_cnt, 1u);
                if (p < 512u) { sel_idx[p] = jbase + c; sel_val[p] = f; }
            }
        }
        o.x = vv[0]; o.y = vv[1]; o.z = vv[2]; o.w = vv[3];
        ((float4*)erow)[tid + i * 256] = o;
    }
    __syncthreads();

    // Sparse decode: dec[r,:] = sum over selected j of v*inv_norm[j]*W[j,:]
    int cnt = (int)min(s_cnt, 512u);
    float a0 = 0.f, a1 = 0.f, a2 = 0.f;
    for (int s = 0; s < cnt; ++s) {
        int j = sel_idx[s];
        float scale = sel_val[s] * inv_norm[j];
        const float* wr = W + (size_t)j * INPUT;
        a0 += scale * wr[tid];
        a1 += scale * wr[tid + 256];
        a2 += scale * wr[tid + 512];
    }
    float* drow = dec + (size_t)r * INPUT;
    drow[tid] = a0;
    drow[tid + 256] = a1;
    drow[tid + 512] = a2;
}

extern "C" void kernel_launch(void* const* d_in, const int* in_sizes, int n_in,
                              void* d_out, int out_size, void* d_ws, size_t ws_size,
                              hipStream_t stream) {
    const float* x = (const float*)d_in[0];   // 4096 x 768
    const float* W = (const float*)d_in[1];   // 16384 x 768
    const float* b = (const float*)d_in[2];   // 16384

    float* dec = (float*)d_out;                         // 4096 x 768
    float* enc = (float*)d_out + (size_t)ROWS * INPUT;  // 4096 x 16384

    float* inv_norm = (float*)d_ws;                     // 16384 floats

    rownorm_kernel<<<HIDDEN / 4, 256, 0, stream>>>(W, inv_norm);
    gemm1_kernel<<<dim3(HIDDEN / BN, ROWS / BM), 256, 0, stream>>>(x, W, b, enc);
    topk_kernel<<<ROWS, 256, 0, stream>>>(enc, W, inv_norm, dec);
}

// Round 3
// 782.389 us; speedup vs baseline: 2.3157x; 2.3157x over previous
//
#include <hip/hip_runtime.h>
#include <hip/hip_bf16.h>
#include <math.h>

#define INPUT 768
#define HIDDEN 16384
#define ROWS 4096
#define KSP 32

typedef unsigned short u16;
typedef __attribute__((ext_vector_type(8))) short bf16x8;
typedef __attribute__((ext_vector_type(4))) float f32x4;

// ---------------- fp32 -> bf16 (hi only) ----------------
__device__ __forceinline__ u16 f2b(float v) {
    __hip_bfloat16 hb = __float2bfloat16(v);
    u16 h; __builtin_memcpy(&h, &hb, 2);
    return h;
}

// One wave per row of x: write bf16 array.
__global__ __launch_bounds__(256) void convx_kernel(const float* __restrict__ x,
                                                    u16* __restrict__ xhi) {
    int row = blockIdx.x * 4 + (threadIdx.x >> 6);
    int lane = threadIdx.x & 63;
    const float4* src = (const float4*)(x + (size_t)row * INPUT);
    #pragma unroll
    for (int i = 0; i < 3; ++i) {
        int c = lane + i * 64;
        float4 v = src[c];
        ushort4 hv = make_ushort4(f2b(v.x), f2b(v.y), f2b(v.z), f2b(v.w));
        *(ushort4*)(xhi + (size_t)row * INPUT + c * 4) = hv;
    }
}

// One wave per row of W: bf16 array + inverse row norm (from fp32).
__global__ __launch_bounds__(256) void convw_kernel(const float* __restrict__ W,
                                                    u16* __restrict__ whi,
                                                    float* __restrict__ inv_norm) {
    int row = blockIdx.x * 4 + (threadIdx.x >> 6);
    int lane = threadIdx.x & 63;
    const float4* src = (const float4*)(W + (size_t)row * INPUT);
    float s = 0.f;
    #pragma unroll
    for (int i = 0; i < 3; ++i) {
        int c = lane + i * 64;
        float4 v = src[c];
        s += v.x * v.x + v.y * v.y + v.z * v.z + v.w * v.w;
        ushort4 hv = make_ushort4(f2b(v.x), f2b(v.y), f2b(v.z), f2b(v.w));
        *(ushort4*)(whi + (size_t)row * INPUT + c * 4) = hv;
    }
    for (int off = 32; off > 0; off >>= 1) s += __shfl_down(s, off, 64);
    if (lane == 0) inv_norm[row] = 1.0f / sqrtf(s);
}

// ---------------- MFMA GEMM (bf16 hi only): pre ~= x @ W^T + b ----------------
#define TM 128
#define TN 128
#define BKK 32

#define GLDS(gp, lp)                                                  \
    __builtin_amdgcn_global_load_lds(                                 \
        (const __attribute__((address_space(1))) void*)(gp),          \
        (__attribute__((address_space(3))) void*)(lp), 16, 0, 0)

__global__ __launch_bounds__(256) void gemm_mfma_kernel(const u16* __restrict__ xhi,
                                                        const u16* __restrict__ whi,
                                                        const float* __restrict__ bias,
                                                        float* __restrict__ pre) {
    __shared__ u16 Ah[TM * BKK];
    __shared__ u16 Bh[TN * BKK];

    const int tid = threadIdx.x;
    const int lane = tid & 63;
    const int wave = tid >> 6;
    const int m0 = blockIdx.y * TM;
    const int n0 = blockIdx.x * TN;
    const int wm = wave >> 1;
    const int wn = wave & 1;

    f32x4 acc[4][4] = {};

    const int r0 = tid >> 2;
    const int k0 = (tid & 3) * 8;
    const size_t aOff0 = (size_t)(m0 + r0) * INPUT + k0;
    const size_t aOff1 = (size_t)(m0 + 64 + r0) * INPUT + k0;
    const size_t bOff0 = (size_t)(n0 + r0) * INPUT + k0;
    const size_t bOff1 = (size_t)(n0 + 64 + r0) * INPUT + k0;
    const int ldsB0 = wave * 512;
    const int ldsB1 = 2048 + wave * 512;

    const int fcol = lane & 15;
    const int koff = (lane >> 4) * 8;

    for (int kt = 0; kt < INPUT; kt += BKK) {
        if (kt) __syncthreads();
        GLDS(xhi + aOff0 + kt, Ah + ldsB0);
        GLDS(xhi + aOff1 + kt, Ah + ldsB1);
        GLDS(whi + bOff0 + kt, Bh + ldsB0);
        GLDS(whi + bOff1 + kt, Bh + ldsB1);
        __syncthreads();

        bf16x8 ah[4], bh[4];
        #pragma unroll
        for (int t = 0; t < 4; ++t) {
            int ai = (wm * 64 + t * 16 + fcol) * BKK + koff;
            int bi = (wn * 64 + t * 16 + fcol) * BKK + koff;
            ah[t] = *(const bf16x8*)(Ah + ai);
            bh[t] = *(const bf16x8*)(Bh + bi);
        }
        #pragma unroll
        for (int mt = 0; mt < 4; ++mt)
            #pragma unroll
            for (int nt = 0; nt < 4; ++nt)
                acc[mt][nt] = __builtin_amdgcn_mfma_f32_16x16x32_bf16(ah[mt], bh[nt], acc[mt][nt], 0, 0, 0);
    }

    // C/D layout: col=lane&15, row=(lane>>4)*4+reg
    const int quad = lane >> 4;
    float bv[4];
    #pragma unroll
    for (int nt = 0; nt < 4; ++nt) bv[nt] = bias[n0 + wn * 64 + nt * 16 + fcol];
    #pragma unroll
    for (int mt = 0; mt < 4; ++mt) {
        int gm = m0 + wm * 64 + mt * 16 + quad * 4;
        #pragma unroll
        for (int nt = 0; nt < 4; ++nt) {
            int gn = n0 + wn * 64 + nt * 16 + fcol;
            float* p = pre + (size_t)gm * HIDDEN + gn;
            #pragma unroll
            for (int r = 0; r < 4; ++r) p[(size_t)r * HIDDEN] = acc[mt][nt][r] + bv[nt];
        }
    }
}

// ---------------- fp32 fallback GEMM (ws too small) ----------------
#define BM 64
#define BN 64
#define BK 16

__global__ __launch_bounds__(256) void rownorm_kernel(const float* __restrict__ W,
                                                      float* __restrict__ inv_norm) {
    int row = blockIdx.x * 4 + (threadIdx.x >> 6);
    int lane = threadIdx.x & 63;
    const float* wr = W + (size_t)row * INPUT;
    float s = 0.f;
    for (int c = lane; c < INPUT; c += 64) { float v = wr[c]; s += v * v; }
    for (int off = 32; off > 0; off >>= 1) s += __shfl_down(s, off, 64);
    if (lane == 0) inv_norm[row] = 1.0f / sqrtf(s);
}

__global__ __launch_bounds__(256) void gemm1_kernel(const float* __restrict__ x,
                                                    const float* __restrict__ W,
                                                    const float* __restrict__ b,
                                                    float* __restrict__ pre) {
    __shared__ float As[BK][BM + 4];
    __shared__ float Bs[BK][BN + 4];
    int tid = threadIdx.x;
    int m0 = blockIdx.y * BM;
    int n0 = blockIdx.x * BN;
    int tx = tid & 15;
    int ty = tid >> 4;
    int lrow = tid >> 2;
    int lk4  = (tid & 3) * 4;

    const float* xa = x + (size_t)(m0 + lrow) * INPUT + lk4;
    const float* wb = W + (size_t)(n0 + lrow) * INPUT + lk4;

    float acc[4][4] = {};

    for (int kt = 0; kt < INPUT; kt += BK) {
        float4 av = *(const float4*)(xa + kt);
        float4 bv = *(const float4*)(wb + kt);
        As[lk4 + 0][lrow] = av.x; As[lk4 + 1][lrow] = av.y;
        As[lk4 + 2][lrow] = av.z; As[lk4 + 3][lrow] = av.w;
        Bs[lk4 + 0][lrow] = bv.x; Bs[lk4 + 1][lrow] = bv.y;
        Bs[lk4 + 2][lrow] = bv.z; Bs[lk4 + 3][lrow] = bv.w;
        __syncthreads();
        #pragma unroll
        for (int k = 0; k < BK; ++k) {
            float4 a4 = *(const float4*)&As[k][ty * 4];
            float4 b4 = *(const float4*)&Bs[k][tx * 4];
            float a[4] = {a4.x, a4.y, a4.z, a4.w};
            float bb[4] = {b4.x, b4.y, b4.z, b4.w};
            #pragma unroll
            for (int i = 0; i < 4; ++i)
                #pragma unroll
                for (int j = 0; j < 4; ++j)
                    acc[i][j] += a[i] * bb[j];
        }
        __syncthreads();
    }

    float bvals[4];
    #pragma unroll
    for (int j = 0; j < 4; ++j) bvals[j] = b[n0 + tx * 4 + j];
    #pragma unroll
    for (int i = 0; i < 4; ++i) {
        int m = m0 + ty * 4 + i;
        float4 o;
        o.x = acc[i][0] + bvals[0];
        o.y = acc[i][1] + bvals[1];
        o.z = acc[i][2] + bvals[2];
        o.w = acc[i][3] + bvals[3];
        *(float4*)(pre + (size_t)m * HIDDEN + n0 + tx * 4) = o;
    }
}

// ---------------- Kernel: approx top-k -> exact candidate recompute -> mask + decode ----------------
__device__ __forceinline__ unsigned int f2key(float f) {
    unsigned int u = __float_as_uint(f);
    return (u & 0x80000000u) ? ~u : (u | 0x80000000u);
}
__device__ __forceinline__ float key2f(unsigned int k) {
    unsigned int u = (k & 0x80000000u) ? (k & 0x7FFFFFFFu) : ~k;
    return __uint_as_float(u);
}

#define DELTA 0.125f
#define MAXC 256

__global__ __launch_bounds__(256) void topk_kernel(float* __restrict__ enc,   // in: approx pre, out: exact masked
                                                   const float* __restrict__ x,
                                                   const float* __restrict__ W,
                                                   const float* __restrict__ b,
                                                   const float* __restrict__ inv_norm,
                                                   float* __restrict__ dec) {
    __shared__ float xs[INPUT];
    __shared__ unsigned int wsum[4];
    __shared__ unsigned int s_cnt;
    __shared__ int   c_idx[MAXC];
    __shared__ float c_exact[MAXC];
    __shared__ float red[4];

    const int tid = threadIdx.x;
    const int lane = tid & 63;
    const int wave = tid >> 6;
    const int r = blockIdx.x;
    float* erow = enc + (size_t)r * HIDDEN;

    // Load approx row as monotonic keys (64 values/thread in regs)
    uint4 u[16];
    #pragma unroll
    for (int i = 0; i < 16; ++i) {
        float4 v = ((const float4*)erow)[tid + i * 256];
        u[i].x = f2key(v.x); u[i].y = f2key(v.y);
        u[i].z = f2key(v.z); u[i].w = f2key(v.w);
    }
    // Stage x row in LDS (fp32) for exact recompute
    #pragma unroll
    for (int i = 0; i < 3; ++i) xs[tid + i * 256] = x[(size_t)r * INPUT + tid + i * 256];
    if (tid == 0) s_cnt = 0;

    // Bisection for approx 32nd-largest key
    unsigned int lo = 0u, hi = 0xFFFFFFFFu;
    for (int it = 0; it < 32; ++it) {
        unsigned int mid = (unsigned int)(((unsigned long long)lo + (unsigned long long)hi + 1ull) >> 1);
        int c = 0;
        #pragma unroll
        for (int i = 0; i < 16; ++i)
            c += (u[i].x >= mid) + (u[i].y >= mid) + (u[i].z >= mid) + (u[i].w >= mid);
        for (int off = 32; off > 0; off >>= 1) c += __shfl_down(c, off, 64);
        if (lane == 0) wsum[wave] = (unsigned int)c;
        __syncthreads();
        unsigned int total = wsum[0] + wsum[1] + wsum[2] + wsum[3];
        if (total >= (unsigned int)KSP) lo = mid; else hi = mid - 1;
        __syncthreads();
    }
    // Candidate threshold: approx 32nd value minus safety margin
    unsigned int ckey = f2key(key2f(lo) - DELTA);

    // Collect candidate indices
    #pragma unroll
    for (int i = 0; i < 16; ++i) {
        int jbase = (tid + i * 256) * 4;
        unsigned int uu[4] = {u[i].x, u[i].y, u[i].z, u[i].w};
        #pragma unroll
        for (int c = 0; c < 4; ++c) {
            if (uu[c] >= ckey) {
                unsigned int p = atomicAdd(&s_cnt, 1u);
                if (p < MAXC) c_idx[p] = jbase + c;
            }
        }
    }
    __syncthreads();
    int cnt = (int)min(s_cnt, (unsigned int)MAXC);

    // Exact fp32 recompute of candidates (wave per candidate, strided)
    for (int c = wave; c < cnt; c += 4) {
        int j = c_idx[c];
        const float* wr = W + (size_t)j * INPUT;
        float s = 0.f;
        #pragma unroll
        for (int i = 0; i < 12; ++i) s += xs[lane + 64 * i] * wr[lane + 64 * i];
        for (int off = 32; off > 0; off >>= 1) s += __shfl_down(s, off, 64);
        if (lane == 0) c_exact[c] = s + b[j];
    }
    __syncthreads();

    // Exact 32nd-largest among candidates (== exact global threshold):
    // rank by strict >, thresh = min{v : rank(v) <= 31}
    float myv = (tid < cnt) ? c_exact[tid] : -1e30f;
    int rank = 0;
    for (int i = 0; i < cnt; ++i) rank += (c_exact[i] > myv);
    float cand = (tid < cnt && rank <= 31) ? myv : 1e30f;
    for (int off = 32; off > 0; off >>= 1) cand = fminf(cand, __shfl_down(cand, off, 64));
    if (lane == 0) red[wave] = cand;
    __syncthreads();
    float thresh = fminf(fminf(red[0], red[1]), fminf(red[2], red[3]));

    // Write encoded: zeros everywhere, then exact values at selected positions
    float4 z4 = make_float4(0.f, 0.f, 0.f, 0.f);
    #pragma unroll
    for (int i = 0; i < 16; ++i) ((float4*)erow)[tid + i * 256] = z4;
    __syncthreads();
    for (int c = tid; c < cnt; c += 256)
        if (c_exact[c] >= thresh) erow[c_idx[c]] = c_exact[c];

    // Sparse decode from exact selected list
    float a0 = 0.f, a1 = 0.f, a2 = 0.f;
    for (int c = 0; c < cnt; ++c) {
        float v = c_exact[c];
        if (v >= thresh) {
            int j = c_idx[c];
            float sc = v * inv_norm[j];
            const float* wr = W + (size_t)j * INPUT;
            a0 += sc * wr[tid];
            a1 += sc * wr[tid + 256];
            a2 += sc * wr[tid + 512];
        }
    }
    float* drow = dec + (size_t)r * INPUT;
    drow[tid] = a0;
    drow[tid + 256] = a1;
    drow[tid + 512] = a2;
}

extern "C" void kernel_launch(void* const* d_in, const int* in_sizes, int n_in,
                              void* d_out, int out_size, void* d_ws, size_t ws_size,
                              hipStream_t stream) {
    const float* x = (const float*)d_in[0];   // 4096 x 768
    const float* W = (const float*)d_in[1];   // 16384 x 768
    const float* b = (const float*)d_in[2];   // 16384

    float* dec = (float*)d_out;                         // 4096 x 768
    float* enc = (float*)d_out + (size_t)ROWS * INPUT;  // 4096 x 16384

    float* inv_norm = (float*)d_ws;                     // 16384 floats

    const size_t need = 65536 + (size_t)(ROWS + HIDDEN) * INPUT * 2;
    if (ws_size >= need) {
        u16* xhi = (u16*)((char*)d_ws + 65536);
        u16* whi = xhi + (size_t)ROWS * INPUT;
        convx_kernel<<<ROWS / 4, 256, 0, stream>>>(x, xhi);
        convw_kernel<<<HIDDEN / 4, 256, 0, stream>>>(W, whi, inv_norm);
        gemm_mfma_kernel<<<dim3(HIDDEN / TN, ROWS / TM), 256, 0, stream>>>(xhi, whi, b, enc);
    } else {
        rownorm_kernel<<<HIDDEN / 4, 256, 0, stream>>>(W, inv_norm);
        gemm1_kernel<<<dim3(HIDDEN / BN, ROWS / BM), 256, 0, stream>>>(x, W, b, enc);
    }
    topk_kernel<<<ROWS, 256, 0, stream>>>(enc, x, W, b, inv_norm, dec);
}